// Round 2
// baseline (211.245 us; speedup 1.0000x reference)
//
#include <hip/hip_runtime.h>
#include <hip/hip_bf16.h>
#include <math.h>
#include <stdint.h>

#define B_    2
#define S_    2048
#define HID_  768
#define NH_   12
#define HD_   64
#define NROWS (B_ * S_)                    // 4096
#define N_HID_ELEM (NROWS * HID_)          // 3145728
#define N_W_ELEM   (HID_ * HID_)           // 589824

typedef __bf16 bf16x8 __attribute__((ext_vector_type(8)));
typedef float  floatx4 __attribute__((ext_vector_type(4)));

// ---------------------------------------------------------------------------
// Detect whether float inputs are fp32 (flag=1) or bf16 (flag=0).
// Even bf16 slots of an fp32 buffer are mantissa garbage with random
// exponents; real bf16 N(0,1) data never exceeds 1e3.
// ---------------------------------------------------------------------------
__global__ void detect_dtype_kernel(const void* __restrict__ hidden,
                                    int* __restrict__ flag)
{
    const __hip_bfloat16* hb = (const __hip_bfloat16*)hidden;
    float x = __bfloat162float(hb[2 * threadIdx.x]);   // even slots
    bool bad = !(fabsf(x) <= 1e3f);                    // catches NaN/inf too
    unsigned long long m = __ballot(bad);
    if (threadIdx.x == 0) *flag = (m != 0ULL) ? 1 : 0;
}

// ---------------------------------------------------------------------------
// Normalize float inputs to bf16 in workspace (passthrough if already bf16).
// ---------------------------------------------------------------------------
__global__ void convert_inputs_kernel(const void* __restrict__ src_hidden,
                                      const void* __restrict__ src_w1,
                                      const void* __restrict__ src_w2,
                                      const int* __restrict__ flag,
                                      __hip_bfloat16* __restrict__ Hb,
                                      __hip_bfloat16* __restrict__ Wqb,
                                      __hip_bfloat16* __restrict__ Wob)
{
    int i = blockIdx.x * blockDim.x + threadIdx.x;
    const int isf = *flag;
    const void* src;
    __hip_bfloat16* dst;
    int off;
    if (i < N_HID_ELEM)                    { src = src_hidden; dst = Hb;  off = i; }
    else if (i < N_HID_ELEM + N_W_ELEM)    { src = src_w1;     dst = Wqb; off = i - N_HID_ELEM; }
    else if (i < N_HID_ELEM + 2 * N_W_ELEM){ src = src_w2;     dst = Wob; off = i - N_HID_ELEM - N_W_ELEM; }
    else return;
    dst[off] = isf ? __float2bfloat16(((const float*)src)[off])
                   : ((const __hip_bfloat16*)src)[off];
}

// ---------------------------------------------------------------------------
// GEMM: C[m][n] = sum_k A[m][k] * W[n][k]  (m97-verified B^T pattern).
// If flagp && *flagp: write fp32 to Cf, else bf16 to C.
// ---------------------------------------------------------------------------
__global__ __launch_bounds__(256) void gemm_bt(
    const __hip_bfloat16* __restrict__ A,
    const __hip_bfloat16* __restrict__ W,
    __hip_bfloat16* __restrict__ C,
    float* __restrict__ Cf,
    const int* __restrict__ flagp,
    int M, int N, int K)
{
    const int wv   = threadIdx.x >> 6;
    const int lane = threadIdx.x & 63;
    const int l16  = lane & 15;
    const int quad = lane >> 4;
    const int m0 = blockIdx.x * 64 + wv * 16;
    const int n0 = blockIdx.y * 64;

    floatx4 acc[4] = {};

    const __hip_bfloat16* Arow  = A + (size_t)(m0 + l16) * K + quad * 8;
    const __hip_bfloat16* Wbase = W + (size_t)(n0 + l16) * K + quad * 8;

    for (int k0 = 0; k0 < K; k0 += 32) {
        bf16x8 a = *reinterpret_cast<const bf16x8*>(Arow + k0);
#pragma unroll
        for (int t = 0; t < 4; ++t) {
            bf16x8 b = *reinterpret_cast<const bf16x8*>(Wbase + (size_t)(t * 16) * K + k0);
            acc[t] = __builtin_amdgcn_mfma_f32_16x16x32_bf16(a, b, acc[t], 0, 0, 0);
        }
    }

    const bool f32out = flagp && (*flagp != 0);
#pragma unroll
    for (int t = 0; t < 4; ++t) {
#pragma unroll
        for (int r = 0; r < 4; ++r) {
            int row = m0 + quad * 4 + r;       // C/D: row = quad*4 + reg
            int col = n0 + t * 16 + l16;       // C/D: col = lane&15
            if (f32out) Cf[(size_t)row * N + col] = acc[t][r];
            else        C [(size_t)row * N + col] = __float2bfloat16(acc[t][r]);
        }
    }
}

// ---------------------------------------------------------------------------
// RoPE: Qr = Q*cos + rotate_half(Q)*sin  (layout [NROWS][NH*HD])
// ---------------------------------------------------------------------------
__global__ void rope_kernel(const __hip_bfloat16* __restrict__ Q,
                            const int* __restrict__ pos_idx,
                            __hip_bfloat16* __restrict__ Qr)
{
    int idx = blockIdx.x * blockDim.x + threadIdx.x;
    if (idx >= NROWS * NH_ * 32) return;
    int f = idx & 31;
    int h = (idx >> 5) % NH_;
    int m = idx / (32 * NH_);
    int s = m % S_;

    float pos = (float)pos_idx[s];
    float inv_freq = powf(10000.0f, -(float)f / 32.0f);
    float ang = pos * inv_freq;
    float sn, cs;
    sincosf(ang, &sn, &cs);

    size_t base = (size_t)m * HID_ + h * HD_ + f;
    float q0 = __bfloat162float(Q[base]);        // dim f
    float q1 = __bfloat162float(Q[base + 32]);   // dim f+32
    Qr[base]      = __float2bfloat16(q0 * cs - q1 * sn);
    Qr[base + 32] = __float2bfloat16(q1 * cs + q0 * sn);
}

// ---------------------------------------------------------------------------
// Banded attention. block = (64-query tile, one (b,h)); 4 waves.
// Window: j in [i0-64, i0+127] (192 keys); row R valid w in [R, R+128].
// ---------------------------------------------------------------------------
__global__ __launch_bounds__(256) void attn_kernel(
    const __hip_bfloat16* __restrict__ Q,    // pre-rope  (= V)
    const __hip_bfloat16* __restrict__ Qr,   // post-rope (= Q = K)
    __hip_bfloat16* __restrict__ O)
{
    __shared__ __align__(16) __hip_bfloat16 Vt[64][200];   // [dim][window]
    __shared__ __align__(16) __hip_bfloat16 Pl[64][200];   // [row][window]

    const int bh = blockIdx.y;
    const int b  = bh / NH_;
    const int h  = bh % NH_;
    const int i0 = blockIdx.x * 64;
    const int tid = threadIdx.x;

    for (int idx = tid; idx < 192 * 64; idx += 256) {
        int w = idx >> 6;
        int d = idx & 63;
        int j = i0 - 64 + w;
        int jc = min(max(j, 0), S_ - 1);
        Vt[d][w] = Q[((size_t)(b * S_ + jc)) * HID_ + h * HD_ + d];
    }
    __syncthreads();

    const int wv   = tid >> 6;
    const int lane = tid & 63;
    const int l16  = lane & 15;
    const int quad = lane >> 4;

    // ---- QK^T: scores[64 q][192 w] ----
    floatx4 sc[12] = {};
    const __hip_bfloat16* qrow =
        Qr + ((size_t)(b * S_ + i0 + wv * 16 + l16)) * HID_ + h * HD_ + quad * 8;
#pragma unroll
    for (int ks = 0; ks < 2; ++ks) {
        bf16x8 a = *reinterpret_cast<const bf16x8*>(qrow + ks * 32);
#pragma unroll
        for (int t = 0; t < 12; ++t) {
            int j = i0 - 64 + t * 16 + l16;
            int jc = min(max(j, 0), S_ - 1);
            bf16x8 bf = *reinterpret_cast<const bf16x8*>(
                Qr + ((size_t)(b * S_ + jc)) * HID_ + h * HD_ + ks * 32 + quad * 8);
            sc[t] = __builtin_amdgcn_mfma_f32_16x16x32_bf16(a, bf, sc[t], 0, 0, 0);
        }
    }

    // ---- masked softmax per row ----
    const float scale = 0.125f;
    float denom[4];
#pragma unroll
    for (int r = 0; r < 4; ++r) {
        const int R = wv * 16 + quad * 4 + r;
        float xv[12];
        float mx = -3.0e38f;
#pragma unroll
        for (int t = 0; t < 12; ++t) {
            int w = t * 16 + l16;
            int j = i0 - 64 + w;
            bool valid = (w >= R) && (w <= R + 128) && (j >= 0) && (j < S_);
            float x = valid ? sc[t][r] * scale : -1.0e30f;
            xv[t] = x;
            mx = fmaxf(mx, x);
        }
#pragma unroll
        for (int msk = 1; msk < 16; msk <<= 1) mx = fmaxf(mx, __shfl_xor(mx, msk, 64));
        float sum = 0.f;
#pragma unroll
        for (int t = 0; t < 12; ++t) {
            float p = __expf(xv[t] - mx);
            sum += p;
            Pl[R][t * 16 + l16] = __float2bfloat16(p);
        }
#pragma unroll
        for (int msk = 1; msk < 16; msk <<= 1) sum += __shfl_xor(sum, msk, 64);
        denom[r] = sum;
    }
    __syncthreads();

    // ---- PV ----
    floatx4 oacc[4] = {};
#pragma unroll
    for (int ks = 0; ks < 6; ++ks) {
        bf16x8 a = *reinterpret_cast<const bf16x8*>(&Pl[wv * 16 + l16][ks * 32 + quad * 8]);
#pragma unroll
        for (int t = 0; t < 4; ++t) {
            bf16x8 bf = *reinterpret_cast<const bf16x8*>(&Vt[t * 16 + l16][ks * 32 + quad * 8]);
            oacc[t] = __builtin_amdgcn_mfma_f32_16x16x32_bf16(a, bf, oacc[t], 0, 0, 0);
        }
    }

#pragma unroll
    for (int t = 0; t < 4; ++t) {
#pragma unroll
        for (int r = 0; r < 4; ++r) {
            int row = i0 + wv * 16 + quad * 4 + r;
            int col = t * 16 + l16;
            O[((size_t)(b * S_ + row)) * HID_ + h * HD_ + col] =
                __float2bfloat16(oacc[t][r] / denom[r]);
        }
    }
}

// ---------------------------------------------------------------------------
extern "C" void kernel_launch(void* const* d_in, const int* in_sizes, int n_in,
                              void* d_out, int out_size, void* d_ws, size_t ws_size,
                              hipStream_t stream)
{
    // Resolve inputs by element count (robust to ordering surprises):
    // hidden=3145728, Wq/Wo=589824 (first=Wq), pos=2048; masks(4194304) unused.
    int ih = -1, iw1 = -1, iw2 = -1, ip = -1;
    for (int i = 0; i < n_in; ++i) {
        int s = in_sizes[i];
        if      (s == N_HID_ELEM && ih < 0) ih = i;
        else if (s == N_W_ELEM)  { if (iw1 < 0) iw1 = i; else if (iw2 < 0) iw2 = i; }
        else if (s == S_ && ip < 0) ip = i;
    }
    if (ih < 0)  ih = 0;
    if (iw1 < 0) iw1 = 1;
    if (iw2 < 0) iw2 = 2;
    if (ip < 0)  ip = 5;

    const void* hidden_raw = d_in[ih];
    const void* w1_raw     = d_in[iw1];
    const void* w2_raw     = d_in[iw2];
    const int*  pos_idx    = (const int*)d_in[ip];

    uint8_t* wsb = (uint8_t*)d_ws;
    int* flag           = (int*)wsb;                                   // 256 B slot
    __hip_bfloat16* Hb  = (__hip_bfloat16*)(wsb + 256);
    __hip_bfloat16* Wqb = Hb  + N_HID_ELEM;
    __hip_bfloat16* Wob = Wqb + N_W_ELEM;
    __hip_bfloat16* Q   = Wob + N_W_ELEM;
    __hip_bfloat16* Qr  = Q   + N_HID_ELEM;
    __hip_bfloat16* AO  = Hb;   // Hb dead after gemm1 — alias to save ws

    detect_dtype_kernel<<<1, 64, 0, stream>>>(hidden_raw, flag);

    int conv_threads = N_HID_ELEM + 2 * N_W_ELEM;
    convert_inputs_kernel<<<(conv_threads + 255) / 256, 256, 0, stream>>>(
        hidden_raw, w1_raw, w2_raw, flag, Hb, Wqb, Wob);

    dim3 gblk(NROWS / 64, HID_ / 64);   // (64, 12)

    gemm_bt<<<gblk, 256, 0, stream>>>(Hb, Wqb, Q, nullptr, nullptr,
                                      NROWS, HID_, HID_);

    int rope_threads = NROWS * NH_ * 32;
    rope_kernel<<<(rope_threads + 255) / 256, 256, 0, stream>>>(Q, pos_idx, Qr);

    attn_kernel<<<dim3(S_ / 64, B_ * NH_), 256, 0, stream>>>(Q, Qr, AO);

    gemm_bt<<<gblk, 256, 0, stream>>>(AO, Wob, (__hip_bfloat16*)d_out,
                                      (float*)d_out, flag, NROWS, HID_, HID_);
}

// Round 5
// 163.136 us; speedup vs baseline: 1.2949x; 1.2949x over previous
//
#include <hip/hip_runtime.h>
#include <hip/hip_bf16.h>
#include <math.h>
#include <stdint.h>

#define B_    2
#define S_    2048
#define HID_  768
#define NH_   12
#define HD_   64
#define NROWS (B_ * S_)                    // 4096
#define N_HID_ELEM (NROWS * HID_)          // 3145728
#define N_W_ELEM   (HID_ * HID_)           // 589824

// attention LDS geometry: 224 staged keys, row stride 232 (16B-aligned,
// bank-friendly: 116 dwords/row -> l16*20 mod 32 covers 8 banks)
#define KW   224
#define KSTR 232

typedef __bf16 bf16x8 __attribute__((ext_vector_type(8)));
typedef float  floatx4 __attribute__((ext_vector_type(4)));

// fp32 -> bf16 conversion of hidden + Wq + Wo, x4 vectorized
__global__ void convert_inputs_kernel(const float* __restrict__ src_hidden,
                                      const float* __restrict__ src_w1,
                                      const float* __restrict__ src_w2,
                                      __hip_bfloat16* __restrict__ Hb,
                                      __hip_bfloat16* __restrict__ Wqb,
                                      __hip_bfloat16* __restrict__ Wob)
{
    int i = blockIdx.x * blockDim.x + threadIdx.x;   // float4 index
    const float* src;
    __hip_bfloat16* dst;
    int off;
    const int NH4 = N_HID_ELEM / 4, NW4 = N_W_ELEM / 4;
    if (i < NH4)           { src = src_hidden; dst = Hb;  off = i; }
    else if (i < NH4+NW4)  { src = src_w1;     dst = Wqb; off = i - NH4; }
    else if (i < NH4+2*NW4){ src = src_w2;     dst = Wob; off = i - NH4 - NW4; }
    else return;
    float4 v = reinterpret_cast<const float4*>(src)[off];
    __hip_bfloat16 o[4] = { __float2bfloat16(v.x), __float2bfloat16(v.y),
                            __float2bfloat16(v.z), __float2bfloat16(v.w) };
    *reinterpret_cast<uint64_t*>(dst + 4 * (size_t)off) = *reinterpret_cast<uint64_t*>(o);
}

__device__ __forceinline__ void gload_lds16(const __hip_bfloat16* g, __hip_bfloat16* l)
{
    __builtin_amdgcn_global_load_lds(
        (const __attribute__((address_space(1))) void*)g,
        (__attribute__((address_space(3))) void*)l, 16, 0, 0);
}

// ---------------------------------------------------------------------------
// m97-style GEMM: C[m][n] = sum_k A[m][k] * W[n][k]
// BM=BN=128, BK=32, 256 threads, 2x2 wave grid, 4x4 16x16 acc per wave.
// MODE 1: fused RoPE -> writes Q(bf16) and Qr(bf16).  MODE 2: fp32 Cf.
// ---------------------------------------------------------------------------
template<int MODE>
__global__ __launch_bounds__(256) void gemm128(
    const __hip_bfloat16* __restrict__ A,
    const __hip_bfloat16* __restrict__ W,
    __hip_bfloat16* __restrict__ C,        // MODE 1: Q
    __hip_bfloat16* __restrict__ C2,       // MODE 1: Qr
    float* __restrict__ Cf,                // MODE 2
    const int* __restrict__ pos_idx,
    int M, int N, int K)
{
    __shared__ __align__(16) __hip_bfloat16 Alds[128 * 32];
    __shared__ __align__(16) __hip_bfloat16 Wlds[128 * 32];

    const int tid  = threadIdx.x;
    const int wv   = tid >> 6;
    const int lane = tid & 63;
    const int l16  = lane & 15;
    const int quad = lane >> 4;
    const int m0 = blockIdx.x * 128;
    const int n0 = blockIdx.y * 128;
    const int wm = (wv >> 1) * 64;          // wave row offset in tile
    const int wn = (wv & 1) * 64;           // wave col offset in tile

    // staging: chunk c in [0,512) -> row=c>>2, col8=(c&3)*8 ; 16B per chunk
    const int c_lane = wv * 64 + lane;
    const int row0 = c_lane >> 2, col80 = (c_lane & 3) * 8;
    const int row1 = (c_lane + 256) >> 2, col81 = ((c_lane + 256) & 3) * 8;

    const __hip_bfloat16* gA0 = A + (size_t)(m0 + row0) * K + col80;
    const __hip_bfloat16* gA1 = A + (size_t)(m0 + row1) * K + col81;
    const __hip_bfloat16* gW0 = W + (size_t)(n0 + row0) * K + col80;
    const __hip_bfloat16* gW1 = W + (size_t)(n0 + row1) * K + col81;
    __hip_bfloat16* lA0 = &Alds[(wv * 64) * 8];          // wave-uniform bases
    __hip_bfloat16* lA1 = &Alds[(wv * 64 + 256) * 8];
    __hip_bfloat16* lW0 = &Wlds[(wv * 64) * 8];
    __hip_bfloat16* lW1 = &Wlds[(wv * 64 + 256) * 8];

    floatx4 acc[4][4] = {};

    for (int k0 = 0; k0 < K; k0 += 32) {
        gload_lds16(gA0 + k0, lA0);
        gload_lds16(gA1 + k0, lA1);
        gload_lds16(gW0 + k0, lW0);
        gload_lds16(gW1 + k0, lW1);
        __syncthreads();

        bf16x8 af[4], bf[4];
#pragma unroll
        for (int t = 0; t < 4; ++t)
            af[t] = *reinterpret_cast<const bf16x8*>(&Alds[(wm + t * 16 + l16) * 32 + quad * 8]);
#pragma unroll
        for (int u = 0; u < 4; ++u)
            bf[u] = *reinterpret_cast<const bf16x8*>(&Wlds[(wn + u * 16 + l16) * 32 + quad * 8]);
#pragma unroll
        for (int t = 0; t < 4; ++t)
#pragma unroll
            for (int u = 0; u < 4; ++u)
                acc[t][u] = __builtin_amdgcn_mfma_f32_16x16x32_bf16(af[t], bf[u], acc[t][u], 0, 0, 0);
        __syncthreads();
    }

    if (MODE == 1) {
        const int nbase = n0 + wn;               // one head per wave-half
#pragma unroll
        for (int t = 0; t < 4; ++t) {
#pragma unroll
            for (int r = 0; r < 4; ++r) {
                int m = m0 + wm + t * 16 + quad * 4 + r;
                int s = m & (S_ - 1);
                float pos = (float)pos_idx[s];
#pragma unroll
                for (int u = 0; u < 2; ++u) {
                    float f = (float)(u * 16 + l16);                 // 0..31
                    float inv = exp2f(f * (-0.41524101186092024f)); // -log2(1e4)/32
                    float sn, cs;
                    sincosf(pos * inv, &sn, &cs);
                    float q0 = acc[t][u][r];
                    float q1 = acc[t][u + 2][r];
                    size_t base = (size_t)m * HID_ + nbase + u * 16 + l16;
                    C [base]      = __float2bfloat16(q0);
                    C [base + 32] = __float2bfloat16(q1);
                    C2[base]      = __float2bfloat16(q0 * cs - q1 * sn);
                    C2[base + 32] = __float2bfloat16(q1 * cs + q0 * sn);
                }
            }
        }
    } else {
#pragma unroll
        for (int t = 0; t < 4; ++t)
#pragma unroll
            for (int u = 0; u < 4; ++u)
#pragma unroll
                for (int r = 0; r < 4; ++r) {
                    int row = m0 + wm + t * 16 + quad * 4 + r;
                    int col = n0 + wn + u * 16 + l16;
                    Cf[(size_t)row * N + col] = acc[t][u][r];
                }
    }
}

// ---------------------------------------------------------------------------
// Banded attention. block = (64-query tile, one (b,h)); 4 waves.
// Staged keys: w in [0,KW) <-> j = i0-64+w. Wave wv rows R in [wv*16,wv*16+16):
// valid w in [R, R+128]; QK/PV work the wave band [wv*16, wv*16+160) -- all
// inside the staged window and the KSTR-stride arrays (max col 207 < 232).
// ---------------------------------------------------------------------------
__global__ __launch_bounds__(256) void attn_kernel(
    const __hip_bfloat16* __restrict__ Q,    // pre-rope  (= V)
    const __hip_bfloat16* __restrict__ Qr,   // post-rope (= Q = K)
    __hip_bfloat16* __restrict__ O)
{
    __shared__ __align__(16) __hip_bfloat16 Vt[64][KSTR];   // [dim][window]
    __shared__ __align__(16) __hip_bfloat16 Pl[64][KSTR];   // [row][window]

    const int bh = blockIdx.y;
    const int b  = bh / NH_;
    const int h  = bh % NH_;
    const int i0 = blockIdx.x * 64;
    const int tid = threadIdx.x;

    for (int idx = tid; idx < KW * 64; idx += 256) {
        int w = idx >> 6;
        int d = idx & 63;
        int j = i0 - 64 + w;
        int jc = min(max(j, 0), S_ - 1);
        Vt[d][w] = Q[((size_t)(b * S_ + jc)) * HID_ + h * HD_ + d];
    }
    __syncthreads();

    const int wv   = tid >> 6;
    const int lane = tid & 63;
    const int l16  = lane & 15;
    const int quad = lane >> 4;

    // ---- QK^T over the 10 tiles intersecting this wave's band ----
    floatx4 sc[10] = {};
    const __hip_bfloat16* qrow =
        Qr + ((size_t)(b * S_ + i0 + wv * 16 + l16)) * HID_ + h * HD_ + quad * 8;
#pragma unroll
    for (int ks = 0; ks < 2; ++ks) {
        bf16x8 a = *reinterpret_cast<const bf16x8*>(qrow + ks * 32);
#pragma unroll
        for (int t = 0; t < 10; ++t) {
            int j = i0 - 64 + (wv + t) * 16 + l16;
            int jc = min(max(j, 0), S_ - 1);
            bf16x8 bfr = *reinterpret_cast<const bf16x8*>(
                Qr + ((size_t)(b * S_ + jc)) * HID_ + h * HD_ + ks * 32 + quad * 8);
            sc[t] = __builtin_amdgcn_mfma_f32_16x16x32_bf16(a, bfr, sc[t], 0, 0, 0);
        }
    }

    // ---- masked softmax per row ----
    const float scale = 0.125f;
    float denom[4];
#pragma unroll
    for (int r = 0; r < 4; ++r) {
        const int R = wv * 16 + quad * 4 + r;
        float xv[10];
        float mx = -3.0e38f;
#pragma unroll
        for (int t = 0; t < 10; ++t) {
            int w = (wv + t) * 16 + l16;
            int j = i0 - 64 + w;
            bool valid = (w >= R) && (w <= R + 128) && (j >= 0) && (j < S_);
            float x = valid ? sc[t][r] * scale : -1.0e30f;
            xv[t] = x;
            mx = fmaxf(mx, x);
        }
#pragma unroll
        for (int msk = 1; msk < 16; msk <<= 1) mx = fmaxf(mx, __shfl_xor(mx, msk, 64));
        float sum = 0.f;
#pragma unroll
        for (int t = 0; t < 10; ++t) {
            float p = __expf(xv[t] - mx);
            sum += p;
            Pl[R][(wv + t) * 16 + l16] = __float2bfloat16(p);
        }
#pragma unroll
        for (int msk = 1; msk < 16; msk <<= 1) sum += __shfl_xor(sum, msk, 64);
        denom[r] = sum;
    }
    __syncthreads();

    // ---- PV over the wave's 160-wide band: k-chunks base wv*16 + c*32 ----
    floatx4 oacc[4] = {};
#pragma unroll
    for (int c = 0; c < 5; ++c) {
        const int base = wv * 16 + c * 32;
        bf16x8 a = *reinterpret_cast<const bf16x8*>(&Pl[wv * 16 + l16][base + quad * 8]);
#pragma unroll
        for (int u = 0; u < 4; ++u) {
            bf16x8 bfr = *reinterpret_cast<const bf16x8*>(&Vt[u * 16 + l16][base + quad * 8]);
            oacc[u] = __builtin_amdgcn_mfma_f32_16x16x32_bf16(a, bfr, oacc[u], 0, 0, 0);
        }
    }

#pragma unroll
    for (int u = 0; u < 4; ++u)
#pragma unroll
        for (int r = 0; r < 4; ++r) {
            int row = i0 + wv * 16 + quad * 4 + r;
            int col = u * 16 + l16;
            O[((size_t)(b * S_ + row)) * HID_ + h * HD_ + col] =
                __float2bfloat16(oacc[u][r] / denom[r]);
        }
}

// ---------------------------------------------------------------------------
extern "C" void kernel_launch(void* const* d_in, const int* in_sizes, int n_in,
                              void* d_out, int out_size, void* d_ws, size_t ws_size,
                              hipStream_t stream)
{
    int ih = -1, iw1 = -1, iw2 = -1, ip = -1;
    for (int i = 0; i < n_in; ++i) {
        int s = in_sizes[i];
        if      (s == N_HID_ELEM && ih < 0) ih = i;
        else if (s == N_W_ELEM)  { if (iw1 < 0) iw1 = i; else if (iw2 < 0) iw2 = i; }
        else if (s == S_ && ip < 0) ip = i;
    }
    if (ih < 0)  ih = 0;
    if (iw1 < 0) iw1 = 1;
    if (iw2 < 0) iw2 = 2;
    if (ip < 0)  ip = 5;

    const float* hidden = (const float*)d_in[ih];
    const float* w1     = (const float*)d_in[iw1];
    const float* w2     = (const float*)d_in[iw2];
    const int*   pos    = (const int*)d_in[ip];

    __hip_bfloat16* Hb  = (__hip_bfloat16*)d_ws;
    __hip_bfloat16* Wqb = Hb  + N_HID_ELEM;
    __hip_bfloat16* Wob = Wqb + N_W_ELEM;
    __hip_bfloat16* Q   = Wob + N_W_ELEM;
    __hip_bfloat16* Qr  = Q   + N_HID_ELEM;
    __hip_bfloat16* AO  = Hb;   // Hb dead after gemm1

    int conv4 = (N_HID_ELEM + 2 * N_W_ELEM) / 4;
    convert_inputs_kernel<<<(conv4 + 255) / 256, 256, 0, stream>>>(
        hidden, w1, w2, Hb, Wqb, Wob);

    dim3 gblk(NROWS / 128, HID_ / 128);   // (32, 6)

    // GEMM1 + fused RoPE -> Q, Qr
    gemm128<1><<<gblk, 256, 0, stream>>>(Hb, Wqb, Q, Qr, nullptr, pos,
                                         NROWS, HID_, HID_);

    attn_kernel<<<dim3(S_ / 64, B_ * NH_), 256, 0, stream>>>(Q, Qr, AO);

    // GEMM2 -> fp32 out
    gemm128<2><<<gblk, 256, 0, stream>>>(AO, Wob, nullptr, nullptr, (float*)d_out,
                                         nullptr, NROWS, HID_, HID_);
}

// Round 6
// 146.197 us; speedup vs baseline: 1.4449x; 1.1159x over previous
//
#include <hip/hip_runtime.h>
#include <hip/hip_bf16.h>
#include <math.h>
#include <stdint.h>

#define B_    2
#define S_    2048
#define HID_  768
#define NH_   12
#define HD_   64
#define NROWS (B_ * S_)                    // 4096
#define N_HID_ELEM (NROWS * HID_)          // 3145728
#define N_W_ELEM   (HID_ * HID_)           // 589824

// attention LDS geometry: 224 staged keys, row stride 232
#define KW   224
#define KSTR 232

typedef __bf16 bf16x8 __attribute__((ext_vector_type(8)));
typedef float  floatx4 __attribute__((ext_vector_type(4)));

// fp32 -> bf16 conversion of hidden + Wq + Wo, x4 vectorized
__global__ void convert_inputs_kernel(const float* __restrict__ src_hidden,
                                      const float* __restrict__ src_w1,
                                      const float* __restrict__ src_w2,
                                      __hip_bfloat16* __restrict__ Hb,
                                      __hip_bfloat16* __restrict__ Wqb,
                                      __hip_bfloat16* __restrict__ Wob)
{
    int i = blockIdx.x * blockDim.x + threadIdx.x;   // float4 index
    const float* src;
    __hip_bfloat16* dst;
    int off;
    const int NH4 = N_HID_ELEM / 4, NW4 = N_W_ELEM / 4;
    if (i < NH4)           { src = src_hidden; dst = Hb;  off = i; }
    else if (i < NH4+NW4)  { src = src_w1;     dst = Wqb; off = i - NH4; }
    else if (i < NH4+2*NW4){ src = src_w2;     dst = Wob; off = i - NH4 - NW4; }
    else return;
    float4 v = reinterpret_cast<const float4*>(src)[off];
    __hip_bfloat16 o[4] = { __float2bfloat16(v.x), __float2bfloat16(v.y),
                            __float2bfloat16(v.z), __float2bfloat16(v.w) };
    *reinterpret_cast<uint64_t*>(dst + 4 * (size_t)off) = *reinterpret_cast<uint64_t*>(o);
}

__device__ __forceinline__ void gload_lds16(const __hip_bfloat16* g, __hip_bfloat16* l)
{
    __builtin_amdgcn_global_load_lds(
        (const __attribute__((address_space(1))) void*)g,
        (__attribute__((address_space(3))) void*)l, 16, 0, 0);
}

// ---------------------------------------------------------------------------
// 64x64-tile GEMM: C[m][n] = sum_k A[m][k] * W[n][k]. BK=64, 256 threads.
// Grid (M/64, N/64) = (64,12) = 768 blocks -> 3 co-resident blocks/CU.
// Wave wv computes rows [wv*16, wv*16+16) x all 64 cols (4 accs).
// LDS: XOR-swizzled (slot = kc ^ (row&7)) -> conflict-free b128 reads while
// keeping global_load_lds's contiguous lane*16B destination requirement.
// MODE 1: fused RoPE -> writes Q(bf16) and Qr(bf16).  MODE 2: fp32 Cf.
// ---------------------------------------------------------------------------
template<int MODE>
__global__ __launch_bounds__(256) void gemm64(
    const __hip_bfloat16* __restrict__ A,
    const __hip_bfloat16* __restrict__ W,
    __hip_bfloat16* __restrict__ C,        // MODE 1: Q
    __hip_bfloat16* __restrict__ C2,       // MODE 1: Qr
    float* __restrict__ Cf,                // MODE 2
    const int* __restrict__ pos_idx,
    int M, int N, int K)
{
    __shared__ __align__(16) __hip_bfloat16 Alds[64 * 64];
    __shared__ __align__(16) __hip_bfloat16 Wlds[64 * 64];

    const int tid  = threadIdx.x;
    const int wv   = tid >> 6;
    const int lane = tid & 63;
    const int l16  = lane & 15;
    const int quad = lane >> 4;
    const int m0 = blockIdx.x * 64;
    const int n0 = blockIdx.y * 64;

    // staging: 512 16B-chunks per tile; thread handles chunks c0 and c0+256.
    // LDS slot c holds global (row=c>>3, kchunk=(c&7)^(row&7)) -- XOR swizzle.
    const int c0 = wv * 64 + lane;
    const int c1 = c0 + 256;
    const int r0 = c0 >> 3, k0c = ((c0 & 7) ^ (r0 & 7)) * 8;
    const int r1 = c1 >> 3, k1c = ((c1 & 7) ^ (r1 & 7)) * 8;

    const __hip_bfloat16* gA0 = A + (size_t)(m0 + r0) * K + k0c;
    const __hip_bfloat16* gA1 = A + (size_t)(m0 + r1) * K + k1c;
    const __hip_bfloat16* gW0 = W + (size_t)(n0 + r0) * K + k0c;
    const __hip_bfloat16* gW1 = W + (size_t)(n0 + r1) * K + k1c;
    __hip_bfloat16* lA0 = &Alds[(wv * 64) * 8];          // wave-uniform bases
    __hip_bfloat16* lA1 = &Alds[(wv * 64 + 256) * 8];
    __hip_bfloat16* lW0 = &Wlds[(wv * 64) * 8];
    __hip_bfloat16* lW1 = &Wlds[(wv * 64 + 256) * 8];

    floatx4 acc[4] = {};
    const int ra = wv * 16 + l16;          // A-fragment row for this lane

    for (int k0 = 0; k0 < K; k0 += 64) {
        gload_lds16(gA0 + k0, lA0);
        gload_lds16(gA1 + k0, lA1);
        gload_lds16(gW0 + k0, lW0);
        gload_lds16(gW1 + k0, lW1);
        __syncthreads();

#pragma unroll
        for (int ks = 0; ks < 2; ++ks) {
            const int kc = ks * 4 + quad;  // 8-elem k-chunk index
            bf16x8 a = *reinterpret_cast<const bf16x8*>(
                &Alds[ra * 64 + ((kc ^ (ra & 7)) * 8)]);
#pragma unroll
            for (int u = 0; u < 4; ++u) {
                const int rw = u * 16 + l16;
                bf16x8 w = *reinterpret_cast<const bf16x8*>(
                    &Wlds[rw * 64 + ((kc ^ (rw & 7)) * 8)]);
                acc[u] = __builtin_amdgcn_mfma_f32_16x16x32_bf16(a, w, acc[u], 0, 0, 0);
            }
        }
        __syncthreads();
    }

    // epilogue: D row = wv*16 + quad*4 + r, col = n0 + u*16 + l16
    if (MODE == 1) {
#pragma unroll
        for (int r = 0; r < 4; ++r) {
            int m = m0 + wv * 16 + quad * 4 + r;
            int s = m & (S_ - 1);
            float pos = (float)pos_idx[s];
#pragma unroll
            for (int u = 0; u < 2; ++u) {
                float f = (float)(u * 16 + l16);                 // 0..31
                float inv = exp2f(f * (-0.41524101186092024f)); // -log2(1e4)/32
                float sn, cs;
                sincosf(pos * inv, &sn, &cs);
                float q0 = acc[u][r];
                float q1 = acc[u + 2][r];
                size_t base = (size_t)m * HID_ + n0 + u * 16 + l16;
                C [base]      = __float2bfloat16(q0);
                C [base + 32] = __float2bfloat16(q1);
                C2[base]      = __float2bfloat16(q0 * cs - q1 * sn);
                C2[base + 32] = __float2bfloat16(q1 * cs + q0 * sn);
            }
        }
    } else {
#pragma unroll
        for (int u = 0; u < 4; ++u)
#pragma unroll
            for (int r = 0; r < 4; ++r) {
                int row = m0 + wv * 16 + quad * 4 + r;
                int col = n0 + u * 16 + l16;
                Cf[(size_t)row * N + col] = acc[u][r];
            }
    }
}

// ---------------------------------------------------------------------------
// Banded attention (unchanged from round 5 -- passed).
// ---------------------------------------------------------------------------
__global__ __launch_bounds__(256) void attn_kernel(
    const __hip_bfloat16* __restrict__ Q,    // pre-rope  (= V)
    const __hip_bfloat16* __restrict__ Qr,   // post-rope (= Q = K)
    __hip_bfloat16* __restrict__ O)
{
    __shared__ __align__(16) __hip_bfloat16 Vt[64][KSTR];   // [dim][window]
    __shared__ __align__(16) __hip_bfloat16 Pl[64][KSTR];   // [row][window]

    const int bh = blockIdx.y;
    const int b  = bh / NH_;
    const int h  = bh % NH_;
    const int i0 = blockIdx.x * 64;
    const int tid = threadIdx.x;

    for (int idx = tid; idx < KW * 64; idx += 256) {
        int w = idx >> 6;
        int d = idx & 63;
        int j = i0 - 64 + w;
        int jc = min(max(j, 0), S_ - 1);
        Vt[d][w] = Q[((size_t)(b * S_ + jc)) * HID_ + h * HD_ + d];
    }
    __syncthreads();

    const int wv   = tid >> 6;
    const int lane = tid & 63;
    const int l16  = lane & 15;
    const int quad = lane >> 4;

    // ---- QK^T over the 10 tiles intersecting this wave's band ----
    floatx4 sc[10] = {};
    const __hip_bfloat16* qrow =
        Qr + ((size_t)(b * S_ + i0 + wv * 16 + l16)) * HID_ + h * HD_ + quad * 8;
#pragma unroll
    for (int ks = 0; ks < 2; ++ks) {
        bf16x8 a = *reinterpret_cast<const bf16x8*>(qrow + ks * 32);
#pragma unroll
        for (int t = 0; t < 10; ++t) {
            int j = i0 - 64 + (wv + t) * 16 + l16;
            int jc = min(max(j, 0), S_ - 1);
            bf16x8 bfr = *reinterpret_cast<const bf16x8*>(
                Qr + ((size_t)(b * S_ + jc)) * HID_ + h * HD_ + ks * 32 + quad * 8);
            sc[t] = __builtin_amdgcn_mfma_f32_16x16x32_bf16(a, bfr, sc[t], 0, 0, 0);
        }
    }

    // ---- masked softmax per row ----
    const float scale = 0.125f;
    float denom[4];
#pragma unroll
    for (int r = 0; r < 4; ++r) {
        const int R = wv * 16 + quad * 4 + r;
        float xv[10];
        float mx = -3.0e38f;
#pragma unroll
        for (int t = 0; t < 10; ++t) {
            int w = (wv + t) * 16 + l16;
            int j = i0 - 64 + w;
            bool valid = (w >= R) && (w <= R + 128) && (j >= 0) && (j < S_);
            float x = valid ? sc[t][r] * scale : -1.0e30f;
            xv[t] = x;
            mx = fmaxf(mx, x);
        }
#pragma unroll
        for (int msk = 1; msk < 16; msk <<= 1) mx = fmaxf(mx, __shfl_xor(mx, msk, 64));
        float sum = 0.f;
#pragma unroll
        for (int t = 0; t < 10; ++t) {
            float p = __expf(xv[t] - mx);
            sum += p;
            Pl[R][(wv + t) * 16 + l16] = __float2bfloat16(p);
        }
#pragma unroll
        for (int msk = 1; msk < 16; msk <<= 1) sum += __shfl_xor(sum, msk, 64);
        denom[r] = sum;
    }
    __syncthreads();

    // ---- PV over the wave's 160-wide band ----
    floatx4 oacc[4] = {};
#pragma unroll
    for (int c = 0; c < 5; ++c) {
        const int base = wv * 16 + c * 32;
        bf16x8 a = *reinterpret_cast<const bf16x8*>(&Pl[wv * 16 + l16][base + quad * 8]);
#pragma unroll
        for (int u = 0; u < 4; ++u) {
            bf16x8 bfr = *reinterpret_cast<const bf16x8*>(&Vt[u * 16 + l16][base + quad * 8]);
            oacc[u] = __builtin_amdgcn_mfma_f32_16x16x32_bf16(a, bfr, oacc[u], 0, 0, 0);
        }
    }

#pragma unroll
    for (int u = 0; u < 4; ++u)
#pragma unroll
        for (int r = 0; r < 4; ++r) {
            int row = i0 + wv * 16 + quad * 4 + r;
            int col = u * 16 + l16;
            O[((size_t)(b * S_ + row)) * HID_ + h * HD_ + col] =
                __float2bfloat16(oacc[u][r] / denom[r]);
        }
}

// ---------------------------------------------------------------------------
extern "C" void kernel_launch(void* const* d_in, const int* in_sizes, int n_in,
                              void* d_out, int out_size, void* d_ws, size_t ws_size,
                              hipStream_t stream)
{
    int ih = -1, iw1 = -1, iw2 = -1, ip = -1;
    for (int i = 0; i < n_in; ++i) {
        int s = in_sizes[i];
        if      (s == N_HID_ELEM && ih < 0) ih = i;
        else if (s == N_W_ELEM)  { if (iw1 < 0) iw1 = i; else if (iw2 < 0) iw2 = i; }
        else if (s == S_ && ip < 0) ip = i;
    }
    if (ih < 0)  ih = 0;
    if (iw1 < 0) iw1 = 1;
    if (iw2 < 0) iw2 = 2;
    if (ip < 0)  ip = 5;

    const float* hidden = (const float*)d_in[ih];
    const float* w1     = (const float*)d_in[iw1];
    const float* w2     = (const float*)d_in[iw2];
    const int*   pos    = (const int*)d_in[ip];

    __hip_bfloat16* Hb  = (__hip_bfloat16*)d_ws;
    __hip_bfloat16* Wqb = Hb  + N_HID_ELEM;
    __hip_bfloat16* Wob = Wqb + N_W_ELEM;
    __hip_bfloat16* Q   = Wob + N_W_ELEM;
    __hip_bfloat16* Qr  = Q   + N_HID_ELEM;
    __hip_bfloat16* AO  = Hb;   // Hb dead after gemm1

    int conv4 = (N_HID_ELEM + 2 * N_W_ELEM) / 4;
    convert_inputs_kernel<<<(conv4 + 255) / 256, 256, 0, stream>>>(
        hidden, w1, w2, Hb, Wqb, Wob);

    dim3 gblk(NROWS / 64, HID_ / 64);   // (64, 12) = 768 blocks

    // GEMM1 + fused RoPE -> Q, Qr
    gemm64<1><<<gblk, 256, 0, stream>>>(Hb, Wqb, Q, Qr, nullptr, pos,
                                        NROWS, HID_, HID_);

    attn_kernel<<<dim3(S_ / 64, B_ * NH_), 256, 0, stream>>>(Q, Qr, AO);

    // GEMM2 -> fp32 out
    gemm64<2><<<gblk, 256, 0, stream>>>(AO, Wob, nullptr, nullptr, (float*)d_out,
                                        nullptr, NROWS, HID_, HID_);
}

// Round 7
// 145.905 us; speedup vs baseline: 1.4478x; 1.0020x over previous
//
#include <hip/hip_runtime.h>
#include <hip/hip_bf16.h>
#include <math.h>
#include <stdint.h>

#define B_    2
#define S_    2048
#define HID_  768
#define NH_   12
#define HD_   64
#define NROWS (B_ * S_)                    // 4096
#define N_HID_ELEM (NROWS * HID_)          // 3145728
#define N_W_ELEM   (HID_ * HID_)           // 589824

// attention LDS geometry: 224 staged keys, row stride 232
#define KW   224
#define KSTR 232

typedef __bf16 bf16x8 __attribute__((ext_vector_type(8)));
typedef float  floatx4 __attribute__((ext_vector_type(4)));

// fp32 -> bf16 conversion of hidden + Wq + Wo, x4 vectorized
__global__ void convert_inputs_kernel(const float* __restrict__ src_hidden,
                                      const float* __restrict__ src_w1,
                                      const float* __restrict__ src_w2,
                                      __hip_bfloat16* __restrict__ Hb,
                                      __hip_bfloat16* __restrict__ Wqb,
                                      __hip_bfloat16* __restrict__ Wob)
{
    int i = blockIdx.x * blockDim.x + threadIdx.x;   // float4 index
    const float* src;
    __hip_bfloat16* dst;
    int off;
    const int NH4 = N_HID_ELEM / 4, NW4 = N_W_ELEM / 4;
    if (i < NH4)           { src = src_hidden; dst = Hb;  off = i; }
    else if (i < NH4+NW4)  { src = src_w1;     dst = Wqb; off = i - NH4; }
    else if (i < NH4+2*NW4){ src = src_w2;     dst = Wob; off = i - NH4 - NW4; }
    else return;
    float4 v = reinterpret_cast<const float4*>(src)[off];
    __hip_bfloat16 o[4] = { __float2bfloat16(v.x), __float2bfloat16(v.y),
                            __float2bfloat16(v.z), __float2bfloat16(v.w) };
    *reinterpret_cast<uint64_t*>(dst + 4 * (size_t)off) = *reinterpret_cast<uint64_t*>(o);
}

__device__ __forceinline__ void gload_lds16(const __hip_bfloat16* g, __hip_bfloat16* l)
{
    __builtin_amdgcn_global_load_lds(
        (const __attribute__((address_space(1))) void*)g,
        (__attribute__((address_space(3))) void*)l, 16, 0, 0);
}

// ---------------------------------------------------------------------------
// 64x64-tile GEMM, m97-faithful staging. C[m][n] = sum_k A[m][k]*W[n][k].
// BK=64 stored as two BK=32 halves: lds[half][row][32] (row stride 64B ->
// 2-way bank aliasing = free). Staging chunk c in [0,256) per half:
// row=c>>2, col8=(c&3)*8 -- lane-contiguous 16B globals (m97 geometry).
// Grid (M/64, N/64) = (64,12) = 768 blocks -> 3 co-resident blocks/CU.
// Wave wv computes rows [wv*16, wv*16+16) x all 64 cols (4 accs).
// MODE 1: fused RoPE -> writes Q(bf16) and Qr(bf16).  MODE 2: fp32 Cf.
// ---------------------------------------------------------------------------
template<int MODE>
__global__ __launch_bounds__(256) void gemm64(
    const __hip_bfloat16* __restrict__ A,
    const __hip_bfloat16* __restrict__ W,
    __hip_bfloat16* __restrict__ C,        // MODE 1: Q
    __hip_bfloat16* __restrict__ C2,       // MODE 1: Qr
    float* __restrict__ Cf,                // MODE 2
    const int* __restrict__ pos_idx,
    int M, int N, int K)
{
    __shared__ __align__(16) __hip_bfloat16 Alds[2][64][32];
    __shared__ __align__(16) __hip_bfloat16 Wlds[2][64][32];

    const int tid  = threadIdx.x;
    const int wv   = tid >> 6;
    const int lane = tid & 63;
    const int l16  = lane & 15;
    const int quad = lane >> 4;
    const int m0 = blockIdx.x * 64;
    const int n0 = blockIdx.y * 64;

    // per-half staging: 256 chunks; thread handles chunk c = wv*64+lane.
    const int c   = wv * 64 + lane;
    const int sr  = c >> 2;                // row 0..63
    const int sc8 = (c & 3) * 8;           // k-offset within 32-half

    const __hip_bfloat16* gA0 = A + (size_t)(m0 + sr) * K + sc8;        // half 0
    const __hip_bfloat16* gA1 = A + (size_t)(m0 + sr) * K + 32 + sc8;   // half 1
    const __hip_bfloat16* gW0 = W + (size_t)(n0 + sr) * K + sc8;
    const __hip_bfloat16* gW1 = W + (size_t)(n0 + sr) * K + 32 + sc8;
    __hip_bfloat16* lA0 = &Alds[0][wv * 16][0];        // wave-uniform bases
    __hip_bfloat16* lA1 = &Alds[1][wv * 16][0];
    __hip_bfloat16* lW0 = &Wlds[0][wv * 16][0];
    __hip_bfloat16* lW1 = &Wlds[1][wv * 16][0];

    floatx4 acc[4] = {};
    const int ra = wv * 16 + l16;          // A-fragment row for this lane

    for (int k0 = 0; k0 < K; k0 += 64) {
        gload_lds16(gA0 + k0, lA0);
        gload_lds16(gA1 + k0, lA1);
        gload_lds16(gW0 + k0, lW0);
        gload_lds16(gW1 + k0, lW1);
        __syncthreads();

#pragma unroll
        for (int ks = 0; ks < 2; ++ks) {
            bf16x8 a = *reinterpret_cast<const bf16x8*>(&Alds[ks][ra][quad * 8]);
#pragma unroll
            for (int u = 0; u < 4; ++u) {
                bf16x8 w = *reinterpret_cast<const bf16x8*>(&Wlds[ks][u * 16 + l16][quad * 8]);
                acc[u] = __builtin_amdgcn_mfma_f32_16x16x32_bf16(a, w, acc[u], 0, 0, 0);
            }
        }
        __syncthreads();
    }

    // epilogue: D row = wv*16 + quad*4 + r, col = n0 + u*16 + l16
    if (MODE == 1) {
#pragma unroll
        for (int r = 0; r < 4; ++r) {
            int m = m0 + wv * 16 + quad * 4 + r;
            int s = m & (S_ - 1);
            float pos = (float)pos_idx[s];
#pragma unroll
            for (int u = 0; u < 2; ++u) {
                float f = (float)(u * 16 + l16);                 // 0..31
                float inv = exp2f(f * (-0.41524101186092024f)); // -log2(1e4)/32
                float sn, cs;
                sincosf(pos * inv, &sn, &cs);
                float q0 = acc[u][r];
                float q1 = acc[u + 2][r];
                size_t base = (size_t)m * HID_ + n0 + u * 16 + l16;
                C [base]      = __float2bfloat16(q0);
                C [base + 32] = __float2bfloat16(q1);
                C2[base]      = __float2bfloat16(q0 * cs - q1 * sn);
                C2[base + 32] = __float2bfloat16(q1 * cs + q0 * sn);
            }
        }
    } else {
#pragma unroll
        for (int u = 0; u < 4; ++u)
#pragma unroll
            for (int r = 0; r < 4; ++r) {
                int row = m0 + wv * 16 + quad * 4 + r;
                int col = n0 + u * 16 + l16;
                Cf[(size_t)row * N + col] = acc[u][r];
            }
    }
}

// ---------------------------------------------------------------------------
// Banded attention (unchanged -- passed r5/r6).
// ---------------------------------------------------------------------------
__global__ __launch_bounds__(256) void attn_kernel(
    const __hip_bfloat16* __restrict__ Q,    // pre-rope  (= V)
    const __hip_bfloat16* __restrict__ Qr,   // post-rope (= Q = K)
    __hip_bfloat16* __restrict__ O)
{
    __shared__ __align__(16) __hip_bfloat16 Vt[64][KSTR];   // [dim][window]
    __shared__ __align__(16) __hip_bfloat16 Pl[64][KSTR];   // [row][window]

    const int bh = blockIdx.y;
    const int b  = bh / NH_;
    const int h  = bh % NH_;
    const int i0 = blockIdx.x * 64;
    const int tid = threadIdx.x;

    for (int idx = tid; idx < KW * 64; idx += 256) {
        int w = idx >> 6;
        int d = idx & 63;
        int j = i0 - 64 + w;
        int jc = min(max(j, 0), S_ - 1);
        Vt[d][w] = Q[((size_t)(b * S_ + jc)) * HID_ + h * HD_ + d];
    }
    __syncthreads();

    const int wv   = tid >> 6;
    const int lane = tid & 63;
    const int l16  = lane & 15;
    const int quad = lane >> 4;

    // ---- QK^T over the 10 tiles intersecting this wave's band ----
    floatx4 sc[10] = {};
    const __hip_bfloat16* qrow =
        Qr + ((size_t)(b * S_ + i0 + wv * 16 + l16)) * HID_ + h * HD_ + quad * 8;
#pragma unroll
    for (int ks = 0; ks < 2; ++ks) {
        bf16x8 a = *reinterpret_cast<const bf16x8*>(qrow + ks * 32);
#pragma unroll
        for (int t = 0; t < 10; ++t) {
            int j = i0 - 64 + (wv + t) * 16 + l16;
            int jc = min(max(j, 0), S_ - 1);
            bf16x8 bfr = *reinterpret_cast<const bf16x8*>(
                Qr + ((size_t)(b * S_ + jc)) * HID_ + h * HD_ + ks * 32 + quad * 8);
            sc[t] = __builtin_amdgcn_mfma_f32_16x16x32_bf16(a, bfr, sc[t], 0, 0, 0);
        }
    }

    // ---- masked softmax per row ----
    const float scale = 0.125f;
    float denom[4];
#pragma unroll
    for (int r = 0; r < 4; ++r) {
        const int R = wv * 16 + quad * 4 + r;
        float xv[10];
        float mx = -3.0e38f;
#pragma unroll
        for (int t = 0; t < 10; ++t) {
            int w = (wv + t) * 16 + l16;
            int j = i0 - 64 + w;
            bool valid = (w >= R) && (w <= R + 128) && (j >= 0) && (j < S_);
            float x = valid ? sc[t][r] * scale : -1.0e30f;
            xv[t] = x;
            mx = fmaxf(mx, x);
        }
#pragma unroll
        for (int msk = 1; msk < 16; msk <<= 1) mx = fmaxf(mx, __shfl_xor(mx, msk, 64));
        float sum = 0.f;
#pragma unroll
        for (int t = 0; t < 10; ++t) {
            float p = __expf(xv[t] - mx);
            sum += p;
            Pl[R][(wv + t) * 16 + l16] = __float2bfloat16(p);
        }
#pragma unroll
        for (int msk = 1; msk < 16; msk <<= 1) sum += __shfl_xor(sum, msk, 64);
        denom[r] = sum;
    }
    __syncthreads();

    // ---- PV over the wave's 160-wide band ----
    floatx4 oacc[4] = {};
#pragma unroll
    for (int c = 0; c < 5; ++c) {
        const int base = wv * 16 + c * 32;
        bf16x8 a = *reinterpret_cast<const bf16x8*>(&Pl[wv * 16 + l16][base + quad * 8]);
#pragma unroll
        for (int u = 0; u < 4; ++u) {
            bf16x8 bfr = *reinterpret_cast<const bf16x8*>(&Vt[u * 16 + l16][base + quad * 8]);
            oacc[u] = __builtin_amdgcn_mfma_f32_16x16x32_bf16(a, bfr, oacc[u], 0, 0, 0);
        }
    }

#pragma unroll
    for (int u = 0; u < 4; ++u)
#pragma unroll
        for (int r = 0; r < 4; ++r) {
            int row = i0 + wv * 16 + quad * 4 + r;
            int col = u * 16 + l16;
            O[((size_t)(b * S_ + row)) * HID_ + h * HD_ + col] =
                __float2bfloat16(oacc[u][r] / denom[r]);
        }
}

// ---------------------------------------------------------------------------
extern "C" void kernel_launch(void* const* d_in, const int* in_sizes, int n_in,
                              void* d_out, int out_size, void* d_ws, size_t ws_size,
                              hipStream_t stream)
{
    int ih = -1, iw1 = -1, iw2 = -1, ip = -1;
    for (int i = 0; i < n_in; ++i) {
        int s = in_sizes[i];
        if      (s == N_HID_ELEM && ih < 0) ih = i;
        else if (s == N_W_ELEM)  { if (iw1 < 0) iw1 = i; else if (iw2 < 0) iw2 = i; }
        else if (s == S_ && ip < 0) ip = i;
    }
    if (ih < 0)  ih = 0;
    if (iw1 < 0) iw1 = 1;
    if (iw2 < 0) iw2 = 2;
    if (ip < 0)  ip = 5;

    const float* hidden = (const float*)d_in[ih];
    const float* w1     = (const float*)d_in[iw1];
    const float* w2     = (const float*)d_in[iw2];
    const int*   pos    = (const int*)d_in[ip];

    __hip_bfloat16* Hb  = (__hip_bfloat16*)d_ws;
    __hip_bfloat16* Wqb = Hb  + N_HID_ELEM;
    __hip_bfloat16* Wob = Wqb + N_W_ELEM;
    __hip_bfloat16* Q   = Wob + N_W_ELEM;
    __hip_bfloat16* Qr  = Q   + N_HID_ELEM;
    __hip_bfloat16* AO  = Hb;   // Hb dead after gemm1

    int conv4 = (N_HID_ELEM + 2 * N_W_ELEM) / 4;
    convert_inputs_kernel<<<(conv4 + 255) / 256, 256, 0, stream>>>(
        hidden, w1, w2, Hb, Wqb, Wob);

    dim3 gblk(NROWS / 64, HID_ / 64);   // (64, 12) = 768 blocks

    // GEMM1 + fused RoPE -> Q, Qr
    gemm64<1><<<gblk, 256, 0, stream>>>(Hb, Wqb, Q, Qr, nullptr, pos,
                                        NROWS, HID_, HID_);

    attn_kernel<<<dim3(S_ / 64, B_ * NH_), 256, 0, stream>>>(Q, Qr, AO);

    // GEMM2 -> fp32 out
    gemm64<2><<<gblk, 256, 0, stream>>>(AO, Wob, nullptr, nullptr, (float*)d_out,
                                        nullptr, NROWS, HID_, HID_);
}